// Round 13
// baseline (634.437 us; speedup 1.0000x reference)
//
#include <hip/hip_runtime.h>
#include <hip/hip_bf16.h>

typedef unsigned short u16;
typedef __attribute__((ext_vector_type(8))) short bf16x8;
typedef __attribute__((ext_vector_type(4))) float f32x4;

#define MFMA16(a,b,c) __builtin_amdgcn_mfma_f32_16x16x32_bf16(a,b,c,0,0,0)

__device__ __forceinline__ u16 f2bf(float f) {
  union { float f; unsigned u; } v; v.f = f;
  return (u16)((v.u + 0x7fffu + ((v.u >> 16) & 1u)) >> 16);
}
__device__ __forceinline__ float bf2f(u16 h) {
  union { unsigned u; float f; } v; v.u = ((unsigned)h) << 16;
  return v.f;
}
// group g in 0..11 (8 qk-head groups of 24q+24k, then 4 v-groups of 48), c in 0..47
__device__ __forceinline__ int qkv_ch(int g, int c) {
  if (g < 8) return (c < 24) ? (g*24 + c) : (192 + g*24 + (c - 24));
  return 384 + (g - 8)*48 + c;
}

// ---------------- K0: pre-permute + bf16-convert qkv weights ------------------------
__global__ __launch_bounds__(256) void k0_wb(
    const float* __restrict__ qkv_w, const float* __restrict__ qkv_b,
    u16* __restrict__ Wb, float* __restrict__ Bp) {
  int j = blockIdx.x*256 + threadIdx.x;          // 432 blocks -> 110592 = 576*192
  int m = j / 192, k = j % 192;
  Wb[j] = f2bf(qkv_w[qkv_ch(m/48, m%48)*192 + k]);
  if (j < 576) Bp[j] = qkv_b[qkv_ch(j/48, j%48)];
}

// ---------------- K1: qkv 1x1 conv, 128-px strips, 512 thr, 3 passes ----------------
// writes qkv1 INTERLEAVED: qkv1[((bb*12+g)*65536 + s)*48 + c]
// Bt: k-major [kO 0..23][px 0..127] 16B slots, XOR swz both sides (0 conflicts, R10/R12)
// R12 traffic pattern (101MB FETCH / 300MB WRITE) + 6 waves/SIMD for MLP (R11 insight).
__global__ __launch_bounds__(512, 6) void k1_qkv(
    const float* __restrict__ x, const u16* __restrict__ Wb,
    const float* __restrict__ Bp, u16* __restrict__ qkv1) {
  int blk = blockIdx.x;               // 2048 = 4 bb * 512 strips
  int bb = blk >> 9, nb = blk & 511;
  int s0 = nb << 7;                   // 128-pixel strip
  int t = threadIdx.x;
  int lane = t & 63, wid = t >> 6;    // 8 waves
  int lg = lane >> 4, lr = lane & 15;
  int wr = wid >> 1, wc = wid & 1;    // wr: group-in-pass (0..3), wc: px half

  __shared__ __align__(16) u16 Bt[24*128*8];  // 49152 B, [kO][px] 16B slots

  // stage x strip: px fast across lanes -> 2 contiguous 512B runs per load instr
  const float* xb = x + (size_t)bb*(192*65536) + s0;
  {
    int px4 = t & 31, kO = t >> 5;    // kO 0..15, round 2: 16..23 (partial)
    #pragma unroll
    for (int rnd = 0; rnd < 2; ++rnd, kO += 16) {
      if (kO < 24) {
        float4 f[8];
        #pragma unroll
        for (int j = 0; j < 8; ++j)
          f[j] = *(const float4*)(xb + (size_t)(kO*8 + j)*65536 + px4*4);
        #pragma unroll
        for (int e = 0; e < 4; ++e) {
          int px = px4*4 + e;
          unsigned w0, w1, w2, w3;
          asm volatile("v_cvt_pk_bf16_f32 %0, %1, %2" : "=v"(w0)
                       : "v"(((const float*)&f[0])[e]), "v"(((const float*)&f[1])[e]));
          asm volatile("v_cvt_pk_bf16_f32 %0, %1, %2" : "=v"(w1)
                       : "v"(((const float*)&f[2])[e]), "v"(((const float*)&f[3])[e]));
          asm volatile("v_cvt_pk_bf16_f32 %0, %1, %2" : "=v"(w2)
                       : "v"(((const float*)&f[4])[e]), "v"(((const float*)&f[5])[e]));
          asm volatile("v_cvt_pk_bf16_f32 %0, %1, %2" : "=v"(w3)
                       : "v"(((const float*)&f[6])[e]), "v"(((const float*)&f[7])[e]));
          int byte = (kO*2048 + px*16) ^ ((px4 & 7) << 4);
          *(uint4*)((char*)Bt + byte) = make_uint4(w0, w1, w2, w3);
        }
      }
    }
  }
  __syncthreads();

  #pragma unroll 1
  for (int pass = 0; pass < 3; ++pass) {
    int g = pass*4 + wr;              // 4 groups per pass, 2 waves (px halves) each
    f32x4 acc[3][4];
    #pragma unroll
    for (int mt = 0; mt < 3; ++mt)
      #pragma unroll
      for (int nt = 0; nt < 4; ++nt)
        acc[mt][nt] = (f32x4){0.f, 0.f, 0.f, 0.f};

    #pragma unroll
    for (int ks = 0; ks < 6; ++ks) {
      bf16x8 af[3], bf[4];
      #pragma unroll
      for (int mt = 0; mt < 3; ++mt)
        af[mt] = *(const bf16x8*)(Wb + (size_t)(g*48 + mt*16 + lr)*192 + ks*32 + lg*8);
      #pragma unroll
      for (int nt = 0; nt < 4; ++nt) {
        int px = wc*64 + nt*16 + lr;
        int byte = ((ks*4 + lg)*2048 + px*16) ^ (((px >> 2) & 7) << 4);
        bf[nt] = *(const bf16x8*)((const char*)Bt + byte);
      }
      #pragma unroll
      for (int mt = 0; mt < 3; ++mt)
        #pragma unroll
        for (int nt = 0; nt < 4; ++nt)
          acc[mt][nt] = MFMA16(af[mt], bf[nt], acc[mt][nt]);
    }

    // epilogue: bias + cvt_pk + direct 8B stores (R12-proven pattern)
    u16* dst = qkv1 + ((size_t)(bb*12 + g)*65536 + s0)*48;
    #pragma unroll
    for (int mt = 0; mt < 3; ++mt) {
      float4 bv = *(const float4*)(Bp + g*48 + mt*16 + lg*4);
      #pragma unroll
      for (int nt = 0; nt < 4; ++nt) {
        int px = wc*64 + nt*16 + lr;
        float a0 = acc[mt][nt][0] + bv.x;
        float a1 = acc[mt][nt][1] + bv.y;
        float a2 = acc[mt][nt][2] + bv.z;
        float a3 = acc[mt][nt][3] + bv.w;
        unsigned w0, w1;
        asm volatile("v_cvt_pk_bf16_f32 %0, %1, %2" : "=v"(w0) : "v"(a0), "v"(a1));
        asm volatile("v_cvt_pk_bf16_f32 %0, %1, %2" : "=v"(w1) : "v"(a2), "v"(a3));
        *(uint2*)(dst + (size_t)px*48 + mt*16 + lg*4) = make_uint2(w0, w1);
      }
    }
  }
}

// ---------------- K2: depthwise 3x3 + MFMA Gram (q,k) + v store ---------------------
// ONE (tile, group, batch) per block (R10-proven, byte-identical).
__global__ __launch_bounds__(256) void k2_dw(
    const u16* __restrict__ qkv1, const float* __restrict__ dw_w,
    const float* __restrict__ dw_b, u16* __restrict__ vd,
    float* __restrict__ partials) {
  int tile = blockIdx.x;              // 0..255
  int tx = tile & 15, ty = tile >> 4;
  int g  = blockIdx.y;                // 0..11
  int bb = blockIdx.z;
  int x0 = tx << 4, y0 = ty << 4;
  int t = threadIdx.x;

  __shared__ __align__(16) u16 buf0[9472];    // 18944 B
  __shared__ __align__(16) u16 buf1[14784];   // 29568 B
  __shared__ float w9[432];
  __shared__ float wb[48];
  float* stg = (float*)buf0;

  for (int j = t; j < 480; j += 256) {
    if (j < 432) { int c = j / 9; w9[j] = dw_w[qkv_ch(g, c)*9 + (j % 9)]; }
    else         { int c = j - 432; wb[c] = dw_b[qkv_ch(g, c)]; }
  }
  if (g < 8)  // zero out_tT pad rows 48..55 (read by Gram frags ak[1])
    for (int j = t; j < 2112; j += 256) buf1[12672 + j] = 0;

  const u16* src = qkv1 + (size_t)(bb*12 + g) * (65536*48);

  #pragma unroll 1
  for (int h = 0; h < 3; ++h) {              // 16-channel thirds
    if (h) __syncthreads();                  // conv(h-1) done reading buf0
    // stage: 324 halo px * 2 uint4 chunks (coalesced: lanes walk px)
    #pragma unroll
    for (int r = 0; r < 3; ++r) {
      int j = t + (r << 8);
      if (j < 648) {
        int hp = j >> 1, c16 = j & 1;
        int hr = hp / 18, hc = hp - hr*18;
        int hy = y0 - 1 + hr, hx = x0 - 1 + hc;
        uint4 v = {0u, 0u, 0u, 0u};
        if (hy >= 0 && hy < 256 && hx >= 0 && hx < 256)
          v = *(const uint4*)(src + ((size_t)hy*256 + hx)*48 + h*16 + c16*8);
        const u16* us = (const u16*)&v;
        int base = c16*(8*456 + 8) + hr*24 + hc;
        #pragma unroll
        for (int cc = 0; cc < 8; ++cc)
          buf0[base + cc*456] = us[cc];
      }
    }
    __syncthreads();

    // conv: 256 items = 16 ch x 16 rows
    {
      int lc = t & 15, row = t >> 4;
      int c = h*16 + lc;
      float wv[9];
      #pragma unroll
      for (int i = 0; i < 9; ++i) wv[i] = w9[c*9 + i];
      float bias = wb[c];
      int ibase = lc*456 + ((lc >> 3) << 3);
      float rowf[3][18];
      #pragma unroll
      for (int dy = 0; dy < 3; ++dy) {
        int base = ibase + (row + dy)*24;
        u16 hrow[18];
        *(uint4*)(hrow)      = *(const uint4*)(buf0 + base);
        *(uint4*)(hrow + 8)  = *(const uint4*)(buf0 + base + 8);
        *(uint*)(hrow + 16)  = *(const uint*)(buf0 + base + 16);
        #pragma unroll
        for (int i2 = 0; i2 < 18; ++i2) rowf[dy][i2] = bf2f(hrow[i2]);
      }
      float o[16];
      #pragma unroll
      for (int p = 0; p < 16; ++p) {
        float a = bias;
        #pragma unroll
        for (int dy = 0; dy < 3; ++dy)
          a += rowf[dy][p]*wv[dy*3] + rowf[dy][p+1]*wv[dy*3+1] + rowf[dy][p+2]*wv[dy*3+2];
        o[p] = a;
      }
      if (g < 8) {
        unsigned ow[8];
        #pragma unroll
        for (int i = 0; i < 8; ++i)
          asm volatile("v_cvt_pk_bf16_f32 %0, %1, %2"
                       : "=v"(ow[i]) : "v"(o[2*i]), "v"(o[2*i + 1]));
        u16* dsth = buf1 + c*264 + row*16;
        *(uint4*)(dsth)     = make_uint4(ow[0], ow[1], ow[2], ow[3]);
        *(uint4*)(dsth + 8) = make_uint4(ow[4], ow[5], ow[6], ow[7]);
      } else {
        int obase = row*792 + c;
        #pragma unroll
        for (int p = 0; p < 16; ++p)
          buf1[obase + p*48] = f2bf(o[p]);
      }
    }
  }
  __syncthreads();

  if (g < 8) {
    // Gram via MFMA: A=q rows 0-23, B=k rows 24-47 of out_tT; diag via mfma(x,x)
    int lane = t & 63, w = t >> 6;
    int lr = lane & 15, lg = lane >> 4;
    f32x4 cc4[8];
    #pragma unroll
    for (int i = 0; i < 8; ++i) cc4[i] = (f32x4){0.f, 0.f, 0.f, 0.f};
    #pragma unroll
    for (int ks = 0; ks < 2; ++ks) {
      int pxb = w*64 + ks*32 + lg*8;
      bf16x8 aq[2], ak[2];
      aq[0] = *(const bf16x8*)(buf1 + (size_t)lr*264 + pxb);
      aq[1] = *(const bf16x8*)(buf1 + (size_t)(16 + lr)*264 + pxb);
      ak[0] = *(const bf16x8*)(buf1 + (size_t)(24 + lr)*264 + pxb);
      ak[1] = *(const bf16x8*)(buf1 + (size_t)(40 + lr)*264 + pxb);
      cc4[0] = MFMA16(aq[0], ak[0], cc4[0]);
      cc4[1] = MFMA16(aq[0], ak[1], cc4[1]);
      cc4[2] = MFMA16(aq[1], ak[0], cc4[2]);
      cc4[3] = MFMA16(aq[1], ak[1], cc4[3]);
      cc4[4] = MFMA16(aq[0], aq[0], cc4[4]);   // qq: diag c 0-15
      cc4[5] = MFMA16(aq[1], aq[1], cc4[5]);   // qq: diag c 16-23
      cc4[6] = MFMA16(ak[0], ak[0], cc4[6]);   // kk: diag d 0-15
      cc4[7] = MFMA16(ak[1], ak[1], cc4[7]);   // kk: diag d 16-23
    }
    // stage cross tiles [w][tile][row*17+col] + diag [w][qk][ch]
    #pragma unroll
    for (int tile2 = 0; tile2 < 4; ++tile2) {
      float* sp = stg + w*1088 + tile2*272 + lr;
      #pragma unroll
      for (int r = 0; r < 4; ++r)
        sp[(lg*4 + r)*17] = cc4[tile2][r];
    }
    {
      int r = lr - lg*4;
      if (r >= 0 && r < 4) {
        stg[4352 + w*96 + lr]      = cc4[4][r];
        stg[4352 + w*96 + 48 + lr] = cc4[6][r];
        if (lr < 8) {
          stg[4352 + w*96 + 16 + lr]      = cc4[5][r];
          stg[4352 + w*96 + 48 + 16 + lr] = cc4[7][r];
        }
      }
    }
    __syncthreads();
    float* pdst = partials + (((size_t)bb*256 + tile)*8 + g) * 640;
    for (int e = t; e < 624; e += 256) {
      float s = 0.f;
      if (e < 576) {
        int c = e / 24, d = e % 24;
        int off = ((c >> 4)*2 + (d >> 4))*272 + (c & 15)*17 + (d & 15);
        #pragma unroll
        for (int w2 = 0; w2 < 4; ++w2) s += stg[w2*1088 + off];
      } else {
        int cc2 = e - 576;                  // 0-23 q, 24-47 k
        int qk = cc2 / 24, ch = cc2 % 24;
        #pragma unroll
        for (int w2 = 0; w2 < 4; ++w2) s += stg[4352 + w2*96 + qk*48 + ch];
      }
      pdst[e] = s;
    }
  } else {
    u16* dst = vd + (size_t)bb * (65536*192);
    #pragma unroll
    for (int i = 0; i < 6; ++i) {
      int j = t + (i << 8);
      int pp = j / 6, c16 = j % 6;
      int py = pp >> 4, px = pp & 15;
      size_t s = (size_t)(y0 + py)*256 + (x0 + px);
      uint4 v = *(const uint4*)(buf1 + pp*48 + py*24 + c16*8);
      *(uint4*)(dst + s*192 + (g - 8)*48 + c16*8) = v;
    }
  }
}

// ---------------- K3a: reduce Gram partials (8 chunks of 32 blocks) -----------------
__global__ __launch_bounds__(256) void k3a(
    const float* __restrict__ partials, float* __restrict__ G2) {
  int bb = blockIdx.x, h = blockIdx.y, ch = blockIdx.z;  // 4,8,8
  int t = threadIdx.x;
  for (int e = t; e < 624; e += 256) {
    const float* p = partials + ((size_t)(bb*256 + ch*32)*8 + h)*640 + e;
    float s = 0.f;
    #pragma unroll 4
    for (int blk = 0; blk < 32; ++blk) s += p[(size_t)blk * (8*640)];
    G2[(size_t)((bb*8 + h)*8 + ch)*640 + e] = s;
  }
}

// ---------------- K3b: norms + softmax + fold proj into M (per bb,h block) ---------
__global__ __launch_bounds__(256) void k3b(
    const float* __restrict__ G2, const float* __restrict__ scale,
    const float* __restrict__ proj_w, u16* __restrict__ M) {
  int bb = blockIdx.x, h = blockIdx.y;
  int t = threadIdx.x;
  __shared__ float Gh[640];
  __shared__ float attn[24*24];
  for (int j = t; j < 640; j += 256) {
    float s = 0.f;
    #pragma unroll
    for (int ch = 0; ch < 8; ++ch)
      s += G2[(size_t)((bb*8 + h)*8 + ch)*640 + j];
    Gh[j] = s;
  }
  __syncthreads();
  if (t < 24) {
    int c = t;
    float qn = fmaxf(sqrtf(fmaxf(Gh[576 + c], 0.f)), 1e-12f);
    float sc = scale[h];
    float L[24];
    float mx = -1e30f;
    #pragma unroll
    for (int d = 0; d < 24; ++d) {
      float kn = fmaxf(sqrtf(fmaxf(Gh[600 + d], 0.f)), 1e-12f);
      L[d] = Gh[c*24 + d] / (qn * kn) * sc;
      mx = fmaxf(mx, L[d]);
    }
    float ssum = 0.f;
    #pragma unroll
    for (int d = 0; d < 24; ++d) { L[d] = __expf(L[d] - mx); ssum += L[d]; }
    float inv = 1.f / ssum;
    #pragma unroll
    for (int d = 0; d < 24; ++d) attn[c*24 + d] = L[d] * inv;
  }
  __syncthreads();
  // M[co][h*24+d] = sum_c P[co][h*24+c] * attn[c][d]   (4608 entries)
  for (int j = t; j < 4608; j += 256) {
    int co = j / 24, d = j % 24;
    const float* Pr = proj_w + co*192 + h*24;
    float s = 0.f;
    #pragma unroll
    for (int c = 0; c < 24; ++c) s += Pr[c] * attn[c*24 + d];
    M[(size_t)bb*36864 + co*192 + h*24 + d] = f2bf(s);
  }
}

// ---------------- K4: y = M_b @ v + proj_b — zero-LDS, zero-barrier GEMM -----------
__global__ __launch_bounds__(256) void k4_out(
    const u16* __restrict__ vd, const u16* __restrict__ M,
    const float* __restrict__ proj_b, float* __restrict__ out) {
  int p = blockIdx.x;                 // 4096, XCD-swizzled
  int xcd = p & 7, q = p >> 3;
  int pr = xcd*512 + q;               // 0..4095
  int bb = pr >> 10, nb = pr & 1023;
  int s0 = nb << 6;                   // 64 pixels
  int t = threadIdx.x;
  int lane = t & 63, wid = t >> 6;    // wave = 48 M-rows x 64 px
  int lg = lane >> 4, lr = lane & 15;

  const u16* Mb = M + (size_t)bb*36864;
  const u16* Bs = vd + ((size_t)bb*65536 + s0)*192;

  f32x4 acc[3][4];
  #pragma unroll
  for (int mt = 0; mt < 3; ++mt)
    #pragma unroll
    for (int nt = 0; nt < 4; ++nt)
      acc[mt][nt] = (f32x4){0.f, 0.f, 0.f, 0.f};

  #pragma unroll
  for (int ks = 0; ks < 6; ++ks) {
    bf16x8 bf[4], af[3];
    #pragma unroll
    for (int nt = 0; nt < 4; ++nt)
      bf[nt] = *(const bf16x8*)(Bs + (size_t)(nt*16 + lr)*192 + ks*32 + lg*8);
    #pragma unroll
    for (int mt = 0; mt < 3; ++mt)
      af[mt] = *(const bf16x8*)(Mb + (size_t)(wid*48 + mt*16 + lr)*192 + ks*32 + lg*8);
    #pragma unroll
    for (int mt = 0; mt < 3; ++mt)
      #pragma unroll
      for (int nt = 0; nt < 4; ++nt)
        acc[mt][nt] = MFMA16(af[mt], bf[nt], acc[mt][nt]);
  }

  float* dst = out + (size_t)bb*(192*65536) + s0;
  #pragma unroll
  for (int mt = 0; mt < 3; ++mt) {
    int m0 = wid*48 + mt*16 + lg*4;
    #pragma unroll
    for (int r = 0; r < 4; ++r) {
      float bias = proj_b[m0 + r];
      #pragma unroll
      for (int nt = 0; nt < 4; ++nt)
        dst[(size_t)(m0 + r)*65536 + nt*16 + lr] = acc[mt][nt][r] + bias;
    }
  }
}

extern "C" void kernel_launch(void* const* d_in, const int* in_sizes, int n_in,
                              void* d_out, int out_size, void* d_ws, size_t ws_size,
                              hipStream_t stream) {
  (void)in_sizes; (void)n_in; (void)out_size; (void)ws_size;
  const float* x      = (const float*)d_in[0];
  const float* qkv_w  = (const float*)d_in[1];
  const float* qkv_b  = (const float*)d_in[2];
  const float* dw_w   = (const float*)d_in[3];
  const float* dw_b   = (const float*)d_in[4];
  const float* scale  = (const float*)d_in[5];
  const float* proj_w = (const float*)d_in[6];
  const float* proj_b = (const float*)d_in[7];
  float* out = (float*)d_out;
  char* ws = (char*)d_ws;

  u16*   qkv1     = (u16*)(ws);                       // interleaved [b][g][s][48]
  u16*   vd       = (u16*)(ws + 301989888ULL);
  float* partials = (float*)(ws + 402653184ULL);
  u16*   Wb       = (u16*)(ws + 402653184ULL);
  float* Bp       = (float*)(ws + 402653184ULL + 221184ULL);
  float* G2       = (float*)(ws);
  u16*   M        = (u16*)(ws + 1048576ULL);

  k0_wb<<<dim3(432), dim3(256), 0, stream>>>(qkv_w, qkv_b, Wb, Bp);
  k1_qkv<<<dim3(2048), dim3(512), 0, stream>>>(x, Wb, Bp, qkv1);
  k2_dw<<<dim3(256, 12, 4), dim3(256), 0, stream>>>(qkv1, dw_w, dw_b, vd, partials);
  k3a<<<dim3(4, 8, 8), dim3(256), 0, stream>>>(partials, G2);
  k3b<<<dim3(4, 8), dim3(256), 0, stream>>>(G2, scale, proj_w, M);
  k4_out<<<dim3(4096), dim3(256), 0, stream>>>(vd, M, proj_b, out);
}

// Round 14
// 571.685 us; speedup vs baseline: 1.1098x; 1.1098x over previous
//
#include <hip/hip_runtime.h>
#include <hip/hip_bf16.h>

typedef unsigned short u16;
typedef __attribute__((ext_vector_type(8))) short bf16x8;
typedef __attribute__((ext_vector_type(4))) float f32x4;

#define MFMA16(a,b,c) __builtin_amdgcn_mfma_f32_16x16x32_bf16(a,b,c,0,0,0)

__device__ __forceinline__ u16 f2bf(float f) {
  union { float f; unsigned u; } v; v.f = f;
  return (u16)((v.u + 0x7fffu + ((v.u >> 16) & 1u)) >> 16);
}
__device__ __forceinline__ float bf2f(u16 h) {
  union { unsigned u; float f; } v; v.u = ((unsigned)h) << 16;
  return v.f;
}
// group g in 0..11 (8 qk-head groups of 24q+24k, then 4 v-groups of 48), c in 0..47
__device__ __forceinline__ int qkv_ch(int g, int c) {
  if (g < 8) return (c < 24) ? (g*24 + c) : (192 + g*24 + (c - 24));
  return 384 + (g - 8)*48 + c;
}

// ---------------- K0: pre-permute + bf16-convert qkv weights ------------------------
__global__ __launch_bounds__(256) void k0_wb(
    const float* __restrict__ qkv_w, const float* __restrict__ qkv_b,
    u16* __restrict__ Wb, float* __restrict__ Bp) {
  int j = blockIdx.x*256 + threadIdx.x;          // 432 blocks -> 110592 = 576*192
  int m = j / 192, k = j % 192;
  Wb[j] = f2bf(qkv_w[qkv_ch(m/48, m%48)*192 + k]);
  if (j < 576) Bp[j] = qkv_b[qkv_ch(j/48, j%48)];
}

// ---------------- K1: qkv 1x1 conv, 128-px strips, 512 thr, 3 passes ----------------
// writes qkv1 INTERLEAVED: qkv1[((bb*12+g)*65536 + s)*48 + c]
// Bt: k-major [kO 0..23][px 0..127] 16B slots, XOR swz both sides (0 conflicts).
// launch_bounds(512,5): VGPR cap ~96 >= ~68 needed -> NO SPILL (R13's (512,6)
// forced VGPR=40 -> 700MB scratch traffic). 512-thr blocks lift the LDS wave
// ceiling to 24/CU; VGPR(68) cap 16/CU -> expect ~50% occupancy at R12 traffic.
__global__ __launch_bounds__(512, 5) void k1_qkv(
    const float* __restrict__ x, const u16* __restrict__ Wb,
    const float* __restrict__ Bp, u16* __restrict__ qkv1) {
  int blk = blockIdx.x;               // 2048 = 4 bb * 512 strips
  int bb = blk >> 9, nb = blk & 511;
  int s0 = nb << 7;                   // 128-pixel strip
  int t = threadIdx.x;
  int lane = t & 63, wid = t >> 6;    // 8 waves
  int lg = lane >> 4, lr = lane & 15;
  int wr = wid >> 1, wc = wid & 1;    // wr: group-in-pass (0..3), wc: px half

  __shared__ __align__(16) u16 Bt[24*128*8];  // 49152 B, [kO][px] 16B slots

  // stage x strip: px fast across lanes -> 2 contiguous 512B runs per load instr
  const float* xb = x + (size_t)bb*(192*65536) + s0;
  {
    int px4 = t & 31, kO = t >> 5;    // kO 0..15, round 2: 16..23 (partial)
    #pragma unroll
    for (int rnd = 0; rnd < 2; ++rnd, kO += 16) {
      if (kO < 24) {
        float4 f[8];
        #pragma unroll
        for (int j = 0; j < 8; ++j)
          f[j] = *(const float4*)(xb + (size_t)(kO*8 + j)*65536 + px4*4);
        #pragma unroll
        for (int e = 0; e < 4; ++e) {
          int px = px4*4 + e;
          unsigned w0, w1, w2, w3;
          asm volatile("v_cvt_pk_bf16_f32 %0, %1, %2" : "=v"(w0)
                       : "v"(((const float*)&f[0])[e]), "v"(((const float*)&f[1])[e]));
          asm volatile("v_cvt_pk_bf16_f32 %0, %1, %2" : "=v"(w1)
                       : "v"(((const float*)&f[2])[e]), "v"(((const float*)&f[3])[e]));
          asm volatile("v_cvt_pk_bf16_f32 %0, %1, %2" : "=v"(w2)
                       : "v"(((const float*)&f[4])[e]), "v"(((const float*)&f[5])[e]));
          asm volatile("v_cvt_pk_bf16_f32 %0, %1, %2" : "=v"(w3)
                       : "v"(((const float*)&f[6])[e]), "v"(((const float*)&f[7])[e]));
          int byte = (kO*2048 + px*16) ^ ((px4 & 7) << 4);
          *(uint4*)((char*)Bt + byte) = make_uint4(w0, w1, w2, w3);
        }
      }
    }
  }
  __syncthreads();

  #pragma unroll 1
  for (int pass = 0; pass < 3; ++pass) {
    int g = pass*4 + wr;              // 4 groups per pass, 2 waves (px halves) each
    f32x4 acc[3][4];
    #pragma unroll
    for (int mt = 0; mt < 3; ++mt)
      #pragma unroll
      for (int nt = 0; nt < 4; ++nt)
        acc[mt][nt] = (f32x4){0.f, 0.f, 0.f, 0.f};

    #pragma unroll
    for (int ks = 0; ks < 6; ++ks) {
      bf16x8 af[3], bf[4];
      #pragma unroll
      for (int mt = 0; mt < 3; ++mt)
        af[mt] = *(const bf16x8*)(Wb + (size_t)(g*48 + mt*16 + lr)*192 + ks*32 + lg*8);
      #pragma unroll
      for (int nt = 0; nt < 4; ++nt) {
        int px = wc*64 + nt*16 + lr;
        int byte = ((ks*4 + lg)*2048 + px*16) ^ (((px >> 2) & 7) << 4);
        bf[nt] = *(const bf16x8*)((const char*)Bt + byte);
      }
      #pragma unroll
      for (int mt = 0; mt < 3; ++mt)
        #pragma unroll
        for (int nt = 0; nt < 4; ++nt)
          acc[mt][nt] = MFMA16(af[mt], bf[nt], acc[mt][nt]);
    }

    // epilogue: bias + cvt_pk + direct 8B stores (R12-proven pattern)
    u16* dst = qkv1 + ((size_t)(bb*12 + g)*65536 + s0)*48;
    #pragma unroll
    for (int mt = 0; mt < 3; ++mt) {
      float4 bv = *(const float4*)(Bp + g*48 + mt*16 + lg*4);
      #pragma unroll
      for (int nt = 0; nt < 4; ++nt) {
        int px = wc*64 + nt*16 + lr;
        float a0 = acc[mt][nt][0] + bv.x;
        float a1 = acc[mt][nt][1] + bv.y;
        float a2 = acc[mt][nt][2] + bv.z;
        float a3 = acc[mt][nt][3] + bv.w;
        unsigned w0, w1;
        asm volatile("v_cvt_pk_bf16_f32 %0, %1, %2" : "=v"(w0) : "v"(a0), "v"(a1));
        asm volatile("v_cvt_pk_bf16_f32 %0, %1, %2" : "=v"(w1) : "v"(a2), "v"(a3));
        *(uint2*)(dst + (size_t)px*48 + mt*16 + lg*4) = make_uint2(w0, w1);
      }
    }
  }
}

// ---------------- K2: depthwise 3x3 + MFMA Gram (q,k) + v store ---------------------
// ONE (tile, group, batch) per block (R10-proven, byte-identical).
__global__ __launch_bounds__(256) void k2_dw(
    const u16* __restrict__ qkv1, const float* __restrict__ dw_w,
    const float* __restrict__ dw_b, u16* __restrict__ vd,
    float* __restrict__ partials) {
  int tile = blockIdx.x;              // 0..255
  int tx = tile & 15, ty = tile >> 4;
  int g  = blockIdx.y;                // 0..11
  int bb = blockIdx.z;
  int x0 = tx << 4, y0 = ty << 4;
  int t = threadIdx.x;

  __shared__ __align__(16) u16 buf0[9472];    // 18944 B
  __shared__ __align__(16) u16 buf1[14784];   // 29568 B
  __shared__ float w9[432];
  __shared__ float wb[48];
  float* stg = (float*)buf0;

  for (int j = t; j < 480; j += 256) {
    if (j < 432) { int c = j / 9; w9[j] = dw_w[qkv_ch(g, c)*9 + (j % 9)]; }
    else         { int c = j - 432; wb[c] = dw_b[qkv_ch(g, c)]; }
  }
  if (g < 8)  // zero out_tT pad rows 48..55 (read by Gram frags ak[1])
    for (int j = t; j < 2112; j += 256) buf1[12672 + j] = 0;

  const u16* src = qkv1 + (size_t)(bb*12 + g) * (65536*48);

  #pragma unroll 1
  for (int h = 0; h < 3; ++h) {              // 16-channel thirds
    if (h) __syncthreads();                  // conv(h-1) done reading buf0
    // stage: 324 halo px * 2 uint4 chunks (coalesced: lanes walk px)
    #pragma unroll
    for (int r = 0; r < 3; ++r) {
      int j = t + (r << 8);
      if (j < 648) {
        int hp = j >> 1, c16 = j & 1;
        int hr = hp / 18, hc = hp - hr*18;
        int hy = y0 - 1 + hr, hx = x0 - 1 + hc;
        uint4 v = {0u, 0u, 0u, 0u};
        if (hy >= 0 && hy < 256 && hx >= 0 && hx < 256)
          v = *(const uint4*)(src + ((size_t)hy*256 + hx)*48 + h*16 + c16*8);
        const u16* us = (const u16*)&v;
        int base = c16*(8*456 + 8) + hr*24 + hc;
        #pragma unroll
        for (int cc = 0; cc < 8; ++cc)
          buf0[base + cc*456] = us[cc];
      }
    }
    __syncthreads();

    // conv: 256 items = 16 ch x 16 rows
    {
      int lc = t & 15, row = t >> 4;
      int c = h*16 + lc;
      float wv[9];
      #pragma unroll
      for (int i = 0; i < 9; ++i) wv[i] = w9[c*9 + i];
      float bias = wb[c];
      int ibase = lc*456 + ((lc >> 3) << 3);
      float rowf[3][18];
      #pragma unroll
      for (int dy = 0; dy < 3; ++dy) {
        int base = ibase + (row + dy)*24;
        u16 hrow[18];
        *(uint4*)(hrow)      = *(const uint4*)(buf0 + base);
        *(uint4*)(hrow + 8)  = *(const uint4*)(buf0 + base + 8);
        *(uint*)(hrow + 16)  = *(const uint*)(buf0 + base + 16);
        #pragma unroll
        for (int i2 = 0; i2 < 18; ++i2) rowf[dy][i2] = bf2f(hrow[i2]);
      }
      float o[16];
      #pragma unroll
      for (int p = 0; p < 16; ++p) {
        float a = bias;
        #pragma unroll
        for (int dy = 0; dy < 3; ++dy)
          a += rowf[dy][p]*wv[dy*3] + rowf[dy][p+1]*wv[dy*3+1] + rowf[dy][p+2]*wv[dy*3+2];
        o[p] = a;
      }
      if (g < 8) {
        unsigned ow[8];
        #pragma unroll
        for (int i = 0; i < 8; ++i)
          asm volatile("v_cvt_pk_bf16_f32 %0, %1, %2"
                       : "=v"(ow[i]) : "v"(o[2*i]), "v"(o[2*i + 1]));
        u16* dsth = buf1 + c*264 + row*16;
        *(uint4*)(dsth)     = make_uint4(ow[0], ow[1], ow[2], ow[3]);
        *(uint4*)(dsth + 8) = make_uint4(ow[4], ow[5], ow[6], ow[7]);
      } else {
        int obase = row*792 + c;
        #pragma unroll
        for (int p = 0; p < 16; ++p)
          buf1[obase + p*48] = f2bf(o[p]);
      }
    }
  }
  __syncthreads();

  if (g < 8) {
    // Gram via MFMA: A=q rows 0-23, B=k rows 24-47 of out_tT; diag via mfma(x,x)
    int lane = t & 63, w = t >> 6;
    int lr = lane & 15, lg = lane >> 4;
    f32x4 cc4[8];
    #pragma unroll
    for (int i = 0; i < 8; ++i) cc4[i] = (f32x4){0.f, 0.f, 0.f, 0.f};
    #pragma unroll
    for (int ks = 0; ks < 2; ++ks) {
      int pxb = w*64 + ks*32 + lg*8;
      bf16x8 aq[2], ak[2];
      aq[0] = *(const bf16x8*)(buf1 + (size_t)lr*264 + pxb);
      aq[1] = *(const bf16x8*)(buf1 + (size_t)(16 + lr)*264 + pxb);
      ak[0] = *(const bf16x8*)(buf1 + (size_t)(24 + lr)*264 + pxb);
      ak[1] = *(const bf16x8*)(buf1 + (size_t)(40 + lr)*264 + pxb);
      cc4[0] = MFMA16(aq[0], ak[0], cc4[0]);
      cc4[1] = MFMA16(aq[0], ak[1], cc4[1]);
      cc4[2] = MFMA16(aq[1], ak[0], cc4[2]);
      cc4[3] = MFMA16(aq[1], ak[1], cc4[3]);
      cc4[4] = MFMA16(aq[0], aq[0], cc4[4]);   // qq: diag c 0-15
      cc4[5] = MFMA16(aq[1], aq[1], cc4[5]);   // qq: diag c 16-23
      cc4[6] = MFMA16(ak[0], ak[0], cc4[6]);   // kk: diag d 0-15
      cc4[7] = MFMA16(ak[1], ak[1], cc4[7]);   // kk: diag d 16-23
    }
    // stage cross tiles [w][tile][row*17+col] + diag [w][qk][ch]
    #pragma unroll
    for (int tile2 = 0; tile2 < 4; ++tile2) {
      float* sp = stg + w*1088 + tile2*272 + lr;
      #pragma unroll
      for (int r = 0; r < 4; ++r)
        sp[(lg*4 + r)*17] = cc4[tile2][r];
    }
    {
      int r = lr - lg*4;
      if (r >= 0 && r < 4) {
        stg[4352 + w*96 + lr]      = cc4[4][r];
        stg[4352 + w*96 + 48 + lr] = cc4[6][r];
        if (lr < 8) {
          stg[4352 + w*96 + 16 + lr]      = cc4[5][r];
          stg[4352 + w*96 + 48 + 16 + lr] = cc4[7][r];
        }
      }
    }
    __syncthreads();
    float* pdst = partials + (((size_t)bb*256 + tile)*8 + g) * 640;
    for (int e = t; e < 624; e += 256) {
      float s = 0.f;
      if (e < 576) {
        int c = e / 24, d = e % 24;
        int off = ((c >> 4)*2 + (d >> 4))*272 + (c & 15)*17 + (d & 15);
        #pragma unroll
        for (int w2 = 0; w2 < 4; ++w2) s += stg[w2*1088 + off];
      } else {
        int cc2 = e - 576;                  // 0-23 q, 24-47 k
        int qk = cc2 / 24, ch = cc2 % 24;
        #pragma unroll
        for (int w2 = 0; w2 < 4; ++w2) s += stg[4352 + w2*96 + qk*48 + ch];
      }
      pdst[e] = s;
    }
  } else {
    u16* dst = vd + (size_t)bb * (65536*192);
    #pragma unroll
    for (int i = 0; i < 6; ++i) {
      int j = t + (i << 8);
      int pp = j / 6, c16 = j % 6;
      int py = pp >> 4, px = pp & 15;
      size_t s = (size_t)(y0 + py)*256 + (x0 + px);
      uint4 v = *(const uint4*)(buf1 + pp*48 + py*24 + c16*8);
      *(uint4*)(dst + s*192 + (g - 8)*48 + c16*8) = v;
    }
  }
}

// ---------------- K3a: reduce Gram partials (8 chunks of 32 blocks) -----------------
__global__ __launch_bounds__(256) void k3a(
    const float* __restrict__ partials, float* __restrict__ G2) {
  int bb = blockIdx.x, h = blockIdx.y, ch = blockIdx.z;  // 4,8,8
  int t = threadIdx.x;
  for (int e = t; e < 624; e += 256) {
    const float* p = partials + ((size_t)(bb*256 + ch*32)*8 + h)*640 + e;
    float s = 0.f;
    #pragma unroll 4
    for (int blk = 0; blk < 32; ++blk) s += p[(size_t)blk * (8*640)];
    G2[(size_t)((bb*8 + h)*8 + ch)*640 + e] = s;
  }
}

// ---------------- K3b: norms + softmax + fold proj into M (per bb,h block) ---------
__global__ __launch_bounds__(256) void k3b(
    const float* __restrict__ G2, const float* __restrict__ scale,
    const float* __restrict__ proj_w, u16* __restrict__ M) {
  int bb = blockIdx.x, h = blockIdx.y;
  int t = threadIdx.x;
  __shared__ float Gh[640];
  __shared__ float attn[24*24];
  for (int j = t; j < 640; j += 256) {
    float s = 0.f;
    #pragma unroll
    for (int ch = 0; ch < 8; ++ch)
      s += G2[(size_t)((bb*8 + h)*8 + ch)*640 + j];
    Gh[j] = s;
  }
  __syncthreads();
  if (t < 24) {
    int c = t;
    float qn = fmaxf(sqrtf(fmaxf(Gh[576 + c], 0.f)), 1e-12f);
    float sc = scale[h];
    float L[24];
    float mx = -1e30f;
    #pragma unroll
    for (int d = 0; d < 24; ++d) {
      float kn = fmaxf(sqrtf(fmaxf(Gh[600 + d], 0.f)), 1e-12f);
      L[d] = Gh[c*24 + d] / (qn * kn) * sc;
      mx = fmaxf(mx, L[d]);
    }
    float ssum = 0.f;
    #pragma unroll
    for (int d = 0; d < 24; ++d) { L[d] = __expf(L[d] - mx); ssum += L[d]; }
    float inv = 1.f / ssum;
    #pragma unroll
    for (int d = 0; d < 24; ++d) attn[c*24 + d] = L[d] * inv;
  }
  __syncthreads();
  // M[co][h*24+d] = sum_c P[co][h*24+c] * attn[c][d]   (4608 entries)
  for (int j = t; j < 4608; j += 256) {
    int co = j / 24, d = j % 24;
    const float* Pr = proj_w + co*192 + h*24;
    float s = 0.f;
    #pragma unroll
    for (int c = 0; c < 24; ++c) s += Pr[c] * attn[c*24 + d];
    M[(size_t)bb*36864 + co*192 + h*24 + d] = f2bf(s);
  }
}

// ---------------- K4: y = M_b @ v + proj_b — zero-LDS, zero-barrier GEMM -----------
__global__ __launch_bounds__(256) void k4_out(
    const u16* __restrict__ vd, const u16* __restrict__ M,
    const float* __restrict__ proj_b, float* __restrict__ out) {
  int p = blockIdx.x;                 // 4096, XCD-swizzled
  int xcd = p & 7, q = p >> 3;
  int pr = xcd*512 + q;               // 0..4095
  int bb = pr >> 10, nb = pr & 1023;
  int s0 = nb << 6;                   // 64 pixels
  int t = threadIdx.x;
  int lane = t & 63, wid = t >> 6;    // wave = 48 M-rows x 64 px
  int lg = lane >> 4, lr = lane & 15;

  const u16* Mb = M + (size_t)bb*36864;
  const u16* Bs = vd + ((size_t)bb*65536 + s0)*192;

  f32x4 acc[3][4];
  #pragma unroll
  for (int mt = 0; mt < 3; ++mt)
    #pragma unroll
    for (int nt = 0; nt < 4; ++nt)
      acc[mt][nt] = (f32x4){0.f, 0.f, 0.f, 0.f};

  #pragma unroll
  for (int ks = 0; ks < 6; ++ks) {
    bf16x8 bf[4], af[3];
    #pragma unroll
    for (int nt = 0; nt < 4; ++nt)
      bf[nt] = *(const bf16x8*)(Bs + (size_t)(nt*16 + lr)*192 + ks*32 + lg*8);
    #pragma unroll
    for (int mt = 0; mt < 3; ++mt)
      af[mt] = *(const bf16x8*)(Mb + (size_t)(wid*48 + mt*16 + lr)*192 + ks*32 + lg*8);
    #pragma unroll
    for (int mt = 0; mt < 3; ++mt)
      #pragma unroll
      for (int nt = 0; nt < 4; ++nt)
        acc[mt][nt] = MFMA16(af[mt], bf[nt], acc[mt][nt]);
  }

  float* dst = out + (size_t)bb*(192*65536) + s0;
  #pragma unroll
  for (int mt = 0; mt < 3; ++mt) {
    int m0 = wid*48 + mt*16 + lg*4;
    #pragma unroll
    for (int r = 0; r < 4; ++r) {
      float bias = proj_b[m0 + r];
      #pragma unroll
      for (int nt = 0; nt < 4; ++nt)
        dst[(size_t)(m0 + r)*65536 + nt*16 + lr] = acc[mt][nt][r] + bias;
    }
  }
}

extern "C" void kernel_launch(void* const* d_in, const int* in_sizes, int n_in,
                              void* d_out, int out_size, void* d_ws, size_t ws_size,
                              hipStream_t stream) {
  (void)in_sizes; (void)n_in; (void)out_size; (void)ws_size;
  const float* x      = (const float*)d_in[0];
  const float* qkv_w  = (const float*)d_in[1];
  const float* qkv_b  = (const float*)d_in[2];
  const float* dw_w   = (const float*)d_in[3];
  const float* dw_b   = (const float*)d_in[4];
  const float* scale  = (const float*)d_in[5];
  const float* proj_w = (const float*)d_in[6];
  const float* proj_b = (const float*)d_in[7];
  float* out = (float*)d_out;
  char* ws = (char*)d_ws;

  u16*   qkv1     = (u16*)(ws);                       // interleaved [b][g][s][48]
  u16*   vd       = (u16*)(ws + 301989888ULL);
  float* partials = (float*)(ws + 402653184ULL);
  u16*   Wb       = (u16*)(ws + 402653184ULL);
  float* Bp       = (float*)(ws + 402653184ULL + 221184ULL);
  float* G2       = (float*)(ws);
  u16*   M        = (u16*)(ws + 1048576ULL);

  k0_wb<<<dim3(432), dim3(256), 0, stream>>>(qkv_w, qkv_b, Wb, Bp);
  k1_qkv<<<dim3(2048), dim3(512), 0, stream>>>(x, Wb, Bp, qkv1);
  k2_dw<<<dim3(256, 12, 4), dim3(256), 0, stream>>>(qkv1, dw_w, dw_b, vd, partials);
  k3a<<<dim3(4, 8, 8), dim3(256), 0, stream>>>(partials, G2);
  k3b<<<dim3(4, 8), dim3(256), 0, stream>>>(G2, scale, proj_w, M);
  k4_out<<<dim3(4096), dim3(256), 0, stream>>>(vd, M, proj_b, out);
}

// Round 15
// 507.033 us; speedup vs baseline: 1.2513x; 1.1275x over previous
//
#include <hip/hip_runtime.h>
#include <hip/hip_bf16.h>

typedef unsigned short u16;
typedef __attribute__((ext_vector_type(8))) short bf16x8;
typedef __attribute__((ext_vector_type(4))) float f32x4;

#define MFMA16(a,b,c) __builtin_amdgcn_mfma_f32_16x16x32_bf16(a,b,c,0,0,0)

__device__ __forceinline__ u16 f2bf(float f) {
  union { float f; unsigned u; } v; v.f = f;
  return (u16)((v.u + 0x7fffu + ((v.u >> 16) & 1u)) >> 16);
}
__device__ __forceinline__ float bf2f(u16 h) {
  union { unsigned u; float f; } v; v.u = ((unsigned)h) << 16;
  return v.f;
}
// group g in 0..11 (8 qk-head groups of 24q+24k, then 4 v-groups of 48), c in 0..47
__device__ __forceinline__ int qkv_ch(int g, int c) {
  if (g < 8) return (c < 24) ? (g*24 + c) : (192 + g*24 + (c - 24));
  return 384 + (g - 8)*48 + c;
}

// ---------------- K0: pre-permute + bf16-convert qkv weights ------------------------
__global__ __launch_bounds__(256) void k0_wb(
    const float* __restrict__ qkv_w, const float* __restrict__ qkv_b,
    u16* __restrict__ Wb, float* __restrict__ Bp) {
  int j = blockIdx.x*256 + threadIdx.x;          // 432 blocks -> 110592 = 576*192
  int m = j / 192, k = j % 192;
  Wb[j] = f2bf(qkv_w[qkv_ch(m/48, m%48)*192 + k]);
  if (j < 576) Bp[j] = qkv_b[qkv_ch(j/48, j%48)];
}

// ---------------- K1: qkv 1x1 conv, 128-px strips, 512 thr, 3 passes ----------------
// writes qkv1 INTERLEAVED: qkv1[((bb*12+g)*65536 + s)*48 + c]
// Bt: k-major [kO 0..23][px 0..127] 16B slots, XOR swz both sides (0 conflicts).
// launch_bounds 2nd arg behaves as min BLOCKS/CU on this hipcc (decoded from
// R10/R13/R14 VGPR caps: 104@(256,5), 40@(512,6), 48@(512,5)). LDS permits 3
// blocks (3x48KB) -> ask (512,3): 24 waves/CU, VGPR cap ~85 >= 68 -> no spill.
__global__ __launch_bounds__(512, 3) void k1_qkv(
    const float* __restrict__ x, const u16* __restrict__ Wb,
    const float* __restrict__ Bp, u16* __restrict__ qkv1) {
  int blk = blockIdx.x;               // 2048 = 4 bb * 512 strips
  int bb = blk >> 9, nb = blk & 511;
  int s0 = nb << 7;                   // 128-pixel strip
  int t = threadIdx.x;
  int lane = t & 63, wid = t >> 6;    // 8 waves
  int lg = lane >> 4, lr = lane & 15;
  int wr = wid >> 1, wc = wid & 1;    // wr: group-in-pass (0..3), wc: px half

  __shared__ __align__(16) u16 Bt[24*128*8];  // 49152 B, [kO][px] 16B slots

  // stage x strip: px fast across lanes -> 2 contiguous 512B runs per load instr
  const float* xb = x + (size_t)bb*(192*65536) + s0;
  {
    int px4 = t & 31, kO = t >> 5;    // kO 0..15, round 2: 16..23 (partial)
    #pragma unroll
    for (int rnd = 0; rnd < 2; ++rnd, kO += 16) {
      if (kO < 24) {
        float4 f[8];
        #pragma unroll
        for (int j = 0; j < 8; ++j)
          f[j] = *(const float4*)(xb + (size_t)(kO*8 + j)*65536 + px4*4);
        #pragma unroll
        for (int e = 0; e < 4; ++e) {
          int px = px4*4 + e;
          unsigned w0, w1, w2, w3;
          asm volatile("v_cvt_pk_bf16_f32 %0, %1, %2" : "=v"(w0)
                       : "v"(((const float*)&f[0])[e]), "v"(((const float*)&f[1])[e]));
          asm volatile("v_cvt_pk_bf16_f32 %0, %1, %2" : "=v"(w1)
                       : "v"(((const float*)&f[2])[e]), "v"(((const float*)&f[3])[e]));
          asm volatile("v_cvt_pk_bf16_f32 %0, %1, %2" : "=v"(w2)
                       : "v"(((const float*)&f[4])[e]), "v"(((const float*)&f[5])[e]));
          asm volatile("v_cvt_pk_bf16_f32 %0, %1, %2" : "=v"(w3)
                       : "v"(((const float*)&f[6])[e]), "v"(((const float*)&f[7])[e]));
          int byte = (kO*2048 + px*16) ^ ((px4 & 7) << 4);
          *(uint4*)((char*)Bt + byte) = make_uint4(w0, w1, w2, w3);
        }
      }
    }
  }
  __syncthreads();

  #pragma unroll 1
  for (int pass = 0; pass < 3; ++pass) {
    int g = pass*4 + wr;              // 4 groups per pass, 2 waves (px halves) each
    f32x4 acc[3][4];
    #pragma unroll
    for (int mt = 0; mt < 3; ++mt)
      #pragma unroll
      for (int nt = 0; nt < 4; ++nt)
        acc[mt][nt] = (f32x4){0.f, 0.f, 0.f, 0.f};

    #pragma unroll
    for (int ks = 0; ks < 6; ++ks) {
      bf16x8 af[3], bf[4];
      #pragma unroll
      for (int mt = 0; mt < 3; ++mt)
        af[mt] = *(const bf16x8*)(Wb + (size_t)(g*48 + mt*16 + lr)*192 + ks*32 + lg*8);
      #pragma unroll
      for (int nt = 0; nt < 4; ++nt) {
        int px = wc*64 + nt*16 + lr;
        int byte = ((ks*4 + lg)*2048 + px*16) ^ (((px >> 2) & 7) << 4);
        bf[nt] = *(const bf16x8*)((const char*)Bt + byte);
      }
      #pragma unroll
      for (int mt = 0; mt < 3; ++mt)
        #pragma unroll
        for (int nt = 0; nt < 4; ++nt)
          acc[mt][nt] = MFMA16(af[mt], bf[nt], acc[mt][nt]);
    }

    // epilogue: bias + cvt_pk + direct 8B stores (R12-proven pattern)
    u16* dst = qkv1 + ((size_t)(bb*12 + g)*65536 + s0)*48;
    #pragma unroll
    for (int mt = 0; mt < 3; ++mt) {
      float4 bv = *(const float4*)(Bp + g*48 + mt*16 + lg*4);
      #pragma unroll
      for (int nt = 0; nt < 4; ++nt) {
        int px = wc*64 + nt*16 + lr;
        float a0 = acc[mt][nt][0] + bv.x;
        float a1 = acc[mt][nt][1] + bv.y;
        float a2 = acc[mt][nt][2] + bv.z;
        float a3 = acc[mt][nt][3] + bv.w;
        unsigned w0, w1;
        asm volatile("v_cvt_pk_bf16_f32 %0, %1, %2" : "=v"(w0) : "v"(a0), "v"(a1));
        asm volatile("v_cvt_pk_bf16_f32 %0, %1, %2" : "=v"(w1) : "v"(a2), "v"(a3));
        *(uint2*)(dst + (size_t)px*48 + mt*16 + lg*4) = make_uint2(w0, w1);
      }
    }
  }
}

// ---------------- K2: depthwise 3x3 + MFMA Gram (q,k) + v store ---------------------
// ONE (tile, group, batch) per block (R10-proven, byte-identical).
__global__ __launch_bounds__(256) void k2_dw(
    const u16* __restrict__ qkv1, const float* __restrict__ dw_w,
    const float* __restrict__ dw_b, u16* __restrict__ vd,
    float* __restrict__ partials) {
  int tile = blockIdx.x;              // 0..255
  int tx = tile & 15, ty = tile >> 4;
  int g  = blockIdx.y;                // 0..11
  int bb = blockIdx.z;
  int x0 = tx << 4, y0 = ty << 4;
  int t = threadIdx.x;

  __shared__ __align__(16) u16 buf0[9472];    // 18944 B
  __shared__ __align__(16) u16 buf1[14784];   // 29568 B
  __shared__ float w9[432];
  __shared__ float wb[48];
  float* stg = (float*)buf0;

  for (int j = t; j < 480; j += 256) {
    if (j < 432) { int c = j / 9; w9[j] = dw_w[qkv_ch(g, c)*9 + (j % 9)]; }
    else         { int c = j - 432; wb[c] = dw_b[qkv_ch(g, c)]; }
  }
  if (g < 8)  // zero out_tT pad rows 48..55 (read by Gram frags ak[1])
    for (int j = t; j < 2112; j += 256) buf1[12672 + j] = 0;

  const u16* src = qkv1 + (size_t)(bb*12 + g) * (65536*48);

  #pragma unroll 1
  for (int h = 0; h < 3; ++h) {              // 16-channel thirds
    if (h) __syncthreads();                  // conv(h-1) done reading buf0
    // stage: 324 halo px * 2 uint4 chunks (coalesced: lanes walk px)
    #pragma unroll
    for (int r = 0; r < 3; ++r) {
      int j = t + (r << 8);
      if (j < 648) {
        int hp = j >> 1, c16 = j & 1;
        int hr = hp / 18, hc = hp - hr*18;
        int hy = y0 - 1 + hr, hx = x0 - 1 + hc;
        uint4 v = {0u, 0u, 0u, 0u};
        if (hy >= 0 && hy < 256 && hx >= 0 && hx < 256)
          v = *(const uint4*)(src + ((size_t)hy*256 + hx)*48 + h*16 + c16*8);
        const u16* us = (const u16*)&v;
        int base = c16*(8*456 + 8) + hr*24 + hc;
        #pragma unroll
        for (int cc = 0; cc < 8; ++cc)
          buf0[base + cc*456] = us[cc];
      }
    }
    __syncthreads();

    // conv: 256 items = 16 ch x 16 rows
    {
      int lc = t & 15, row = t >> 4;
      int c = h*16 + lc;
      float wv[9];
      #pragma unroll
      for (int i = 0; i < 9; ++i) wv[i] = w9[c*9 + i];
      float bias = wb[c];
      int ibase = lc*456 + ((lc >> 3) << 3);
      float rowf[3][18];
      #pragma unroll
      for (int dy = 0; dy < 3; ++dy) {
        int base = ibase + (row + dy)*24;
        u16 hrow[18];
        *(uint4*)(hrow)      = *(const uint4*)(buf0 + base);
        *(uint4*)(hrow + 8)  = *(const uint4*)(buf0 + base + 8);
        *(uint*)(hrow + 16)  = *(const uint*)(buf0 + base + 16);
        #pragma unroll
        for (int i2 = 0; i2 < 18; ++i2) rowf[dy][i2] = bf2f(hrow[i2]);
      }
      float o[16];
      #pragma unroll
      for (int p = 0; p < 16; ++p) {
        float a = bias;
        #pragma unroll
        for (int dy = 0; dy < 3; ++dy)
          a += rowf[dy][p]*wv[dy*3] + rowf[dy][p+1]*wv[dy*3+1] + rowf[dy][p+2]*wv[dy*3+2];
        o[p] = a;
      }
      if (g < 8) {
        unsigned ow[8];
        #pragma unroll
        for (int i = 0; i < 8; ++i)
          asm volatile("v_cvt_pk_bf16_f32 %0, %1, %2"
                       : "=v"(ow[i]) : "v"(o[2*i]), "v"(o[2*i + 1]));
        u16* dsth = buf1 + c*264 + row*16;
        *(uint4*)(dsth)     = make_uint4(ow[0], ow[1], ow[2], ow[3]);
        *(uint4*)(dsth + 8) = make_uint4(ow[4], ow[5], ow[6], ow[7]);
      } else {
        int obase = row*792 + c;
        #pragma unroll
        for (int p = 0; p < 16; ++p)
          buf1[obase + p*48] = f2bf(o[p]);
      }
    }
  }
  __syncthreads();

  if (g < 8) {
    // Gram via MFMA: A=q rows 0-23, B=k rows 24-47 of out_tT; diag via mfma(x,x)
    int lane = t & 63, w = t >> 6;
    int lr = lane & 15, lg = lane >> 4;
    f32x4 cc4[8];
    #pragma unroll
    for (int i = 0; i < 8; ++i) cc4[i] = (f32x4){0.f, 0.f, 0.f, 0.f};
    #pragma unroll
    for (int ks = 0; ks < 2; ++ks) {
      int pxb = w*64 + ks*32 + lg*8;
      bf16x8 aq[2], ak[2];
      aq[0] = *(const bf16x8*)(buf1 + (size_t)lr*264 + pxb);
      aq[1] = *(const bf16x8*)(buf1 + (size_t)(16 + lr)*264 + pxb);
      ak[0] = *(const bf16x8*)(buf1 + (size_t)(24 + lr)*264 + pxb);
      ak[1] = *(const bf16x8*)(buf1 + (size_t)(40 + lr)*264 + pxb);
      cc4[0] = MFMA16(aq[0], ak[0], cc4[0]);
      cc4[1] = MFMA16(aq[0], ak[1], cc4[1]);
      cc4[2] = MFMA16(aq[1], ak[0], cc4[2]);
      cc4[3] = MFMA16(aq[1], ak[1], cc4[3]);
      cc4[4] = MFMA16(aq[0], aq[0], cc4[4]);   // qq: diag c 0-15
      cc4[5] = MFMA16(aq[1], aq[1], cc4[5]);   // qq: diag c 16-23
      cc4[6] = MFMA16(ak[0], ak[0], cc4[6]);   // kk: diag d 0-15
      cc4[7] = MFMA16(ak[1], ak[1], cc4[7]);   // kk: diag d 16-23
    }
    // stage cross tiles [w][tile][row*17+col] + diag [w][qk][ch]
    #pragma unroll
    for (int tile2 = 0; tile2 < 4; ++tile2) {
      float* sp = stg + w*1088 + tile2*272 + lr;
      #pragma unroll
      for (int r = 0; r < 4; ++r)
        sp[(lg*4 + r)*17] = cc4[tile2][r];
    }
    {
      int r = lr - lg*4;
      if (r >= 0 && r < 4) {
        stg[4352 + w*96 + lr]      = cc4[4][r];
        stg[4352 + w*96 + 48 + lr] = cc4[6][r];
        if (lr < 8) {
          stg[4352 + w*96 + 16 + lr]      = cc4[5][r];
          stg[4352 + w*96 + 48 + 16 + lr] = cc4[7][r];
        }
      }
    }
    __syncthreads();
    float* pdst = partials + (((size_t)bb*256 + tile)*8 + g) * 640;
    for (int e = t; e < 624; e += 256) {
      float s = 0.f;
      if (e < 576) {
        int c = e / 24, d = e % 24;
        int off = ((c >> 4)*2 + (d >> 4))*272 + (c & 15)*17 + (d & 15);
        #pragma unroll
        for (int w2 = 0; w2 < 4; ++w2) s += stg[w2*1088 + off];
      } else {
        int cc2 = e - 576;                  // 0-23 q, 24-47 k
        int qk = cc2 / 24, ch = cc2 % 24;
        #pragma unroll
        for (int w2 = 0; w2 < 4; ++w2) s += stg[4352 + w2*96 + qk*48 + ch];
      }
      pdst[e] = s;
    }
  } else {
    u16* dst = vd + (size_t)bb * (65536*192);
    #pragma unroll
    for (int i = 0; i < 6; ++i) {
      int j = t + (i << 8);
      int pp = j / 6, c16 = j % 6;
      int py = pp >> 4, px = pp & 15;
      size_t s = (size_t)(y0 + py)*256 + (x0 + px);
      uint4 v = *(const uint4*)(buf1 + pp*48 + py*24 + c16*8);
      *(uint4*)(dst + s*192 + (g - 8)*48 + c16*8) = v;
    }
  }
}

// ---------------- K3a: reduce Gram partials (8 chunks of 32 blocks) -----------------
__global__ __launch_bounds__(256) void k3a(
    const float* __restrict__ partials, float* __restrict__ G2) {
  int bb = blockIdx.x, h = blockIdx.y, ch = blockIdx.z;  // 4,8,8
  int t = threadIdx.x;
  for (int e = t; e < 624; e += 256) {
    const float* p = partials + ((size_t)(bb*256 + ch*32)*8 + h)*640 + e;
    float s = 0.f;
    #pragma unroll 4
    for (int blk = 0; blk < 32; ++blk) s += p[(size_t)blk * (8*640)];
    G2[(size_t)((bb*8 + h)*8 + ch)*640 + e] = s;
  }
}

// ---------------- K3b: norms + softmax + fold proj into M (per bb,h block) ---------
__global__ __launch_bounds__(256) void k3b(
    const float* __restrict__ G2, const float* __restrict__ scale,
    const float* __restrict__ proj_w, u16* __restrict__ M) {
  int bb = blockIdx.x, h = blockIdx.y;
  int t = threadIdx.x;
  __shared__ float Gh[640];
  __shared__ float attn[24*24];
  for (int j = t; j < 640; j += 256) {
    float s = 0.f;
    #pragma unroll
    for (int ch = 0; ch < 8; ++ch)
      s += G2[(size_t)((bb*8 + h)*8 + ch)*640 + j];
    Gh[j] = s;
  }
  __syncthreads();
  if (t < 24) {
    int c = t;
    float qn = fmaxf(sqrtf(fmaxf(Gh[576 + c], 0.f)), 1e-12f);
    float sc = scale[h];
    float L[24];
    float mx = -1e30f;
    #pragma unroll
    for (int d = 0; d < 24; ++d) {
      float kn = fmaxf(sqrtf(fmaxf(Gh[600 + d], 0.f)), 1e-12f);
      L[d] = Gh[c*24 + d] / (qn * kn) * sc;
      mx = fmaxf(mx, L[d]);
    }
    float ssum = 0.f;
    #pragma unroll
    for (int d = 0; d < 24; ++d) { L[d] = __expf(L[d] - mx); ssum += L[d]; }
    float inv = 1.f / ssum;
    #pragma unroll
    for (int d = 0; d < 24; ++d) attn[c*24 + d] = L[d] * inv;
  }
  __syncthreads();
  // M[co][h*24+d] = sum_c P[co][h*24+c] * attn[c][d]   (4608 entries)
  for (int j = t; j < 4608; j += 256) {
    int co = j / 24, d = j % 24;
    const float* Pr = proj_w + co*192 + h*24;
    float s = 0.f;
    #pragma unroll
    for (int c = 0; c < 24; ++c) s += Pr[c] * attn[c*24 + d];
    M[(size_t)bb*36864 + co*192 + h*24 + d] = f2bf(s);
  }
}

// ---------------- K4: y = M_b @ v + proj_b — zero-LDS, zero-barrier GEMM -----------
__global__ __launch_bounds__(256) void k4_out(
    const u16* __restrict__ vd, const u16* __restrict__ M,
    const float* __restrict__ proj_b, float* __restrict__ out) {
  int p = blockIdx.x;                 // 4096, XCD-swizzled
  int xcd = p & 7, q = p >> 3;
  int pr = xcd*512 + q;               // 0..4095
  int bb = pr >> 10, nb = pr & 1023;
  int s0 = nb << 6;                   // 64 pixels
  int t = threadIdx.x;
  int lane = t & 63, wid = t >> 6;    // wave = 48 M-rows x 64 px
  int lg = lane >> 4, lr = lane & 15;

  const u16* Mb = M + (size_t)bb*36864;
  const u16* Bs = vd + ((size_t)bb*65536 + s0)*192;

  f32x4 acc[3][4];
  #pragma unroll
  for (int mt = 0; mt < 3; ++mt)
    #pragma unroll
    for (int nt = 0; nt < 4; ++nt)
      acc[mt][nt] = (f32x4){0.f, 0.f, 0.f, 0.f};

  #pragma unroll
  for (int ks = 0; ks < 6; ++ks) {
    bf16x8 bf[4], af[3];
    #pragma unroll
    for (int nt = 0; nt < 4; ++nt)
      bf[nt] = *(const bf16x8*)(Bs + (size_t)(nt*16 + lr)*192 + ks*32 + lg*8);
    #pragma unroll
    for (int mt = 0; mt < 3; ++mt)
      af[mt] = *(const bf16x8*)(Mb + (size_t)(wid*48 + mt*16 + lr)*192 + ks*32 + lg*8);
    #pragma unroll
    for (int mt = 0; mt < 3; ++mt)
      #pragma unroll
      for (int nt = 0; nt < 4; ++nt)
        acc[mt][nt] = MFMA16(af[mt], bf[nt], acc[mt][nt]);
  }

  float* dst = out + (size_t)bb*(192*65536) + s0;
  #pragma unroll
  for (int mt = 0; mt < 3; ++mt) {
    int m0 = wid*48 + mt*16 + lg*4;
    #pragma unroll
    for (int r = 0; r < 4; ++r) {
      float bias = proj_b[m0 + r];
      #pragma unroll
      for (int nt = 0; nt < 4; ++nt)
        dst[(size_t)(m0 + r)*65536 + nt*16 + lr] = acc[mt][nt][r] + bias;
    }
  }
}

extern "C" void kernel_launch(void* const* d_in, const int* in_sizes, int n_in,
                              void* d_out, int out_size, void* d_ws, size_t ws_size,
                              hipStream_t stream) {
  (void)in_sizes; (void)n_in; (void)out_size; (void)ws_size;
  const float* x      = (const float*)d_in[0];
  const float* qkv_w  = (const float*)d_in[1];
  const float* qkv_b  = (const float*)d_in[2];
  const float* dw_w   = (const float*)d_in[3];
  const float* dw_b   = (const float*)d_in[4];
  const float* scale  = (const float*)d_in[5];
  const float* proj_w = (const float*)d_in[6];
  const float* proj_b = (const float*)d_in[7];
  float* out = (float*)d_out;
  char* ws = (char*)d_ws;

  u16*   qkv1     = (u16*)(ws);                       // interleaved [b][g][s][48]
  u16*   vd       = (u16*)(ws + 301989888ULL);
  float* partials = (float*)(ws + 402653184ULL);
  u16*   Wb       = (u16*)(ws + 402653184ULL);
  float* Bp       = (float*)(ws + 402653184ULL + 221184ULL);
  float* G2       = (float*)(ws);
  u16*   M        = (u16*)(ws + 1048576ULL);

  k0_wb<<<dim3(432), dim3(256), 0, stream>>>(qkv_w, qkv_b, Wb, Bp);
  k1_qkv<<<dim3(2048), dim3(512), 0, stream>>>(x, Wb, Bp, qkv1);
  k2_dw<<<dim3(256, 12, 4), dim3(256), 0, stream>>>(qkv1, dw_w, dw_b, vd, partials);
  k3a<<<dim3(4, 8, 8), dim3(256), 0, stream>>>(partials, G2);
  k3b<<<dim3(4, 8), dim3(256), 0, stream>>>(G2, scale, proj_w, M);
  k4_out<<<dim3(4096), dim3(256), 0, stream>>>(vd, M, proj_b, out);
}

// Round 16
// 505.283 us; speedup vs baseline: 1.2556x; 1.0035x over previous
//
#include <hip/hip_runtime.h>
#include <hip/hip_bf16.h>

typedef unsigned short u16;
typedef __attribute__((ext_vector_type(8))) short bf16x8;
typedef __attribute__((ext_vector_type(4))) float f32x4;

#define MFMA16(a,b,c) __builtin_amdgcn_mfma_f32_16x16x32_bf16(a,b,c,0,0,0)

__device__ __forceinline__ u16 f2bf(float f) {
  union { float f; unsigned u; } v; v.f = f;
  return (u16)((v.u + 0x7fffu + ((v.u >> 16) & 1u)) >> 16);
}
__device__ __forceinline__ float bf2f(u16 h) {
  union { unsigned u; float f; } v; v.u = ((unsigned)h) << 16;
  return v.f;
}
// group g in 0..11 (8 qk-head groups of 24q+24k, then 4 v-groups of 48), c in 0..47
__device__ __forceinline__ int qkv_ch(int g, int c) {
  if (g < 8) return (c < 24) ? (g*24 + c) : (192 + g*24 + (c - 24));
  return 384 + (g - 8)*48 + c;
}

// ---------------- K0: pre-permute + bf16-convert qkv weights ------------------------
__global__ __launch_bounds__(256) void k0_wb(
    const float* __restrict__ qkv_w, const float* __restrict__ qkv_b,
    u16* __restrict__ Wb, float* __restrict__ Bp) {
  int j = blockIdx.x*256 + threadIdx.x;          // 432 blocks -> 110592 = 576*192
  int m = j / 192, k = j % 192;
  Wb[j] = f2bf(qkv_w[qkv_ch(m/48, m%48)*192 + k]);
  if (j < 576) Bp[j] = qkv_b[qkv_ch(j/48, j%48)];
}

// ---------------- K1: qkv 1x1 conv, 128-px strips, 512 thr, 3 passes ----------------
// (R15-proven: launch_bounds(512,3) -> no spill, 24 waves/CU ceiling)
__global__ __launch_bounds__(512, 3) void k1_qkv(
    const float* __restrict__ x, const u16* __restrict__ Wb,
    const float* __restrict__ Bp, u16* __restrict__ qkv1) {
  int blk = blockIdx.x;               // 2048 = 4 bb * 512 strips
  int bb = blk >> 9, nb = blk & 511;
  int s0 = nb << 7;                   // 128-pixel strip
  int t = threadIdx.x;
  int lane = t & 63, wid = t >> 6;    // 8 waves
  int lg = lane >> 4, lr = lane & 15;
  int wr = wid >> 1, wc = wid & 1;    // wr: group-in-pass (0..3), wc: px half

  __shared__ __align__(16) u16 Bt[24*128*8];  // 49152 B, [kO][px] 16B slots

  // stage x strip: px fast across lanes -> 2 contiguous 512B runs per load instr
  const float* xb = x + (size_t)bb*(192*65536) + s0;
  {
    int px4 = t & 31, kO = t >> 5;    // kO 0..15, round 2: 16..23 (partial)
    #pragma unroll
    for (int rnd = 0; rnd < 2; ++rnd, kO += 16) {
      if (kO < 24) {
        float4 f[8];
        #pragma unroll
        for (int j = 0; j < 8; ++j)
          f[j] = *(const float4*)(xb + (size_t)(kO*8 + j)*65536 + px4*4);
        #pragma unroll
        for (int e = 0; e < 4; ++e) {
          int px = px4*4 + e;
          unsigned w0, w1, w2, w3;
          asm volatile("v_cvt_pk_bf16_f32 %0, %1, %2" : "=v"(w0)
                       : "v"(((const float*)&f[0])[e]), "v"(((const float*)&f[1])[e]));
          asm volatile("v_cvt_pk_bf16_f32 %0, %1, %2" : "=v"(w1)
                       : "v"(((const float*)&f[2])[e]), "v"(((const float*)&f[3])[e]));
          asm volatile("v_cvt_pk_bf16_f32 %0, %1, %2" : "=v"(w2)
                       : "v"(((const float*)&f[4])[e]), "v"(((const float*)&f[5])[e]));
          asm volatile("v_cvt_pk_bf16_f32 %0, %1, %2" : "=v"(w3)
                       : "v"(((const float*)&f[6])[e]), "v"(((const float*)&f[7])[e]));
          int byte = (kO*2048 + px*16) ^ ((px4 & 7) << 4);
          *(uint4*)((char*)Bt + byte) = make_uint4(w0, w1, w2, w3);
        }
      }
    }
  }
  __syncthreads();

  #pragma unroll 1
  for (int pass = 0; pass < 3; ++pass) {
    int g = pass*4 + wr;              // 4 groups per pass, 2 waves (px halves) each
    f32x4 acc[3][4];
    #pragma unroll
    for (int mt = 0; mt < 3; ++mt)
      #pragma unroll
      for (int nt = 0; nt < 4; ++nt)
        acc[mt][nt] = (f32x4){0.f, 0.f, 0.f, 0.f};

    #pragma unroll
    for (int ks = 0; ks < 6; ++ks) {
      bf16x8 af[3], bf[4];
      #pragma unroll
      for (int mt = 0; mt < 3; ++mt)
        af[mt] = *(const bf16x8*)(Wb + (size_t)(g*48 + mt*16 + lr)*192 + ks*32 + lg*8);
      #pragma unroll
      for (int nt = 0; nt < 4; ++nt) {
        int px = wc*64 + nt*16 + lr;
        int byte = ((ks*4 + lg)*2048 + px*16) ^ (((px >> 2) & 7) << 4);
        bf[nt] = *(const bf16x8*)((const char*)Bt + byte);
      }
      #pragma unroll
      for (int mt = 0; mt < 3; ++mt)
        #pragma unroll
        for (int nt = 0; nt < 4; ++nt)
          acc[mt][nt] = MFMA16(af[mt], bf[nt], acc[mt][nt]);
    }

    // epilogue: bias + cvt_pk + direct 8B stores (R12-proven pattern)
    u16* dst = qkv1 + ((size_t)(bb*12 + g)*65536 + s0)*48;
    #pragma unroll
    for (int mt = 0; mt < 3; ++mt) {
      float4 bv = *(const float4*)(Bp + g*48 + mt*16 + lg*4);
      #pragma unroll
      for (int nt = 0; nt < 4; ++nt) {
        int px = wc*64 + nt*16 + lr;
        float a0 = acc[mt][nt][0] + bv.x;
        float a1 = acc[mt][nt][1] + bv.y;
        float a2 = acc[mt][nt][2] + bv.z;
        float a3 = acc[mt][nt][3] + bv.w;
        unsigned w0, w1;
        asm volatile("v_cvt_pk_bf16_f32 %0, %1, %2" : "=v"(w0) : "v"(a0), "v"(a1));
        asm volatile("v_cvt_pk_bf16_f32 %0, %1, %2" : "=v"(w1) : "v"(a2), "v"(a3));
        *(uint2*)(dst + (size_t)px*48 + mt*16 + lg*4) = make_uint2(w0, w1);
      }
    }
  }
}

// ---------------- K2: depthwise 3x3 (v_dot2_f32_bf16) + MFMA Gram + v store ---------
// ONE (tile, group, batch) per block. Addresses byte-identical to R15; conv inner
// loop rewritten: 9 aligned bf16-pairs per row, 2 dot2 per output per dy, 0 converts.
__global__ __launch_bounds__(256) void k2_dw(
    const u16* __restrict__ qkv1, const float* __restrict__ dw_w,
    const float* __restrict__ dw_b, u16* __restrict__ vd,
    float* __restrict__ partials) {
  int tile = blockIdx.x;              // 0..255
  int tx = tile & 15, ty = tile >> 4;
  int g  = blockIdx.y;                // 0..11
  int bb = blockIdx.z;
  int x0 = tx << 4, y0 = ty << 4;
  int t = threadIdx.x;

  __shared__ __align__(16) u16 buf0[9472];    // 18944 B
  __shared__ __align__(16) u16 buf1[14784];   // 29568 B
  __shared__ float w9[432];
  __shared__ float wb[48];
  float* stg = (float*)buf0;

  for (int j = t; j < 480; j += 256) {
    if (j < 432) { int c = j / 9; w9[j] = dw_w[qkv_ch(g, c)*9 + (j % 9)]; }
    else         { int c = j - 432; wb[c] = dw_b[qkv_ch(g, c)]; }
  }
  if (g < 8)  // zero out_tT pad rows 48..55 (read by Gram frags ak[1])
    for (int j = t; j < 2112; j += 256) buf1[12672 + j] = 0;

  const u16* src = qkv1 + (size_t)(bb*12 + g) * (65536*48);

  #pragma unroll 1
  for (int h = 0; h < 3; ++h) {              // 16-channel thirds
    if (h) __syncthreads();                  // conv(h-1) done reading buf0
    // stage: 324 halo px * 2 uint4 chunks (coalesced: lanes walk px)
    #pragma unroll
    for (int r = 0; r < 3; ++r) {
      int j = t + (r << 8);
      if (j < 648) {
        int hp = j >> 1, c16 = j & 1;
        int hr = hp / 18, hc = hp - hr*18;
        int hy = y0 - 1 + hr, hx = x0 - 1 + hc;
        uint4 v = {0u, 0u, 0u, 0u};
        if (hy >= 0 && hy < 256 && hx >= 0 && hx < 256)
          v = *(const uint4*)(src + ((size_t)hy*256 + hx)*48 + h*16 + c16*8);
        const u16* us = (const u16*)&v;
        int base = c16*(8*456 + 8) + hr*24 + hc;
        #pragma unroll
        for (int cc = 0; cc < 8; ++cc)
          buf0[base + cc*456] = us[cc];
      }
    }
    __syncthreads();

    // conv: 256 items = 16 ch x 16 rows; v_dot2_f32_bf16, aligned pairs only
    {
      int lc = t & 15, row = t >> 4;
      int c = h*16 + lc;
      // packed weight pairs per dy: {w0,w1},{w2,0},{0,w0},{w1,w2}
      unsigned wp[3][4];
      #pragma unroll
      for (int dy = 0; dy < 3; ++dy) {
        float w0 = w9[c*9 + dy*3], w1 = w9[c*9 + dy*3 + 1], w2 = w9[c*9 + dy*3 + 2];
        float z = 0.f;
        asm volatile("v_cvt_pk_bf16_f32 %0, %1, %2" : "=v"(wp[dy][0]) : "v"(w0), "v"(w1));
        asm volatile("v_cvt_pk_bf16_f32 %0, %1, %2" : "=v"(wp[dy][1]) : "v"(w2), "v"(z));
        asm volatile("v_cvt_pk_bf16_f32 %0, %1, %2" : "=v"(wp[dy][2]) : "v"(z),  "v"(w0));
        asm volatile("v_cvt_pk_bf16_f32 %0, %1, %2" : "=v"(wp[dy][3]) : "v"(w1), "v"(w2));
      }
      float bias = wb[c];
      int ibase = lc*456 + ((lc >> 3) << 3);
      unsigned D[3][9];                      // 9 aligned bf16 pairs per halo row
      #pragma unroll
      for (int dy = 0; dy < 3; ++dy) {
        int base = ibase + (row + dy)*24;
        *(uint4*)(&D[dy][0]) = *(const uint4*)(buf0 + base);
        *(uint4*)(&D[dy][4]) = *(const uint4*)(buf0 + base + 8);
        D[dy][8] = *(const unsigned*)(buf0 + base + 16);
      }
      float o[16];
      #pragma unroll
      for (int p = 0; p < 16; ++p) {
        float a = bias;
        int i0 = p >> 1;
        #pragma unroll
        for (int dy = 0; dy < 3; ++dy) {
          if ((p & 1) == 0) {
            asm volatile("v_dot2_f32_bf16 %0, %1, %2, %0"
                         : "+v"(a) : "v"(D[dy][i0]), "v"(wp[dy][0]));
            asm volatile("v_dot2_f32_bf16 %0, %1, %2, %0"
                         : "+v"(a) : "v"(D[dy][i0 + 1]), "v"(wp[dy][1]));
          } else {
            asm volatile("v_dot2_f32_bf16 %0, %1, %2, %0"
                         : "+v"(a) : "v"(D[dy][i0]), "v"(wp[dy][2]));
            asm volatile("v_dot2_f32_bf16 %0, %1, %2, %0"
                         : "+v"(a) : "v"(D[dy][i0 + 1]), "v"(wp[dy][3]));
          }
        }
        o[p] = a;
      }
      if (g < 8) {
        unsigned ow[8];
        #pragma unroll
        for (int i = 0; i < 8; ++i)
          asm volatile("v_cvt_pk_bf16_f32 %0, %1, %2"
                       : "=v"(ow[i]) : "v"(o[2*i]), "v"(o[2*i + 1]));
        u16* dsth = buf1 + c*264 + row*16;
        *(uint4*)(dsth)     = make_uint4(ow[0], ow[1], ow[2], ow[3]);
        *(uint4*)(dsth + 8) = make_uint4(ow[4], ow[5], ow[6], ow[7]);
      } else {
        int obase = row*792 + c;
        #pragma unroll
        for (int p = 0; p < 16; ++p)
          buf1[obase + p*48] = f2bf(o[p]);
      }
    }
  }
  __syncthreads();

  if (g < 8) {
    // Gram via MFMA: A=q rows 0-23, B=k rows 24-47 of out_tT; diag via mfma(x,x)
    int lane = t & 63, w = t >> 6;
    int lr = lane & 15, lg = lane >> 4;
    f32x4 cc4[8];
    #pragma unroll
    for (int i = 0; i < 8; ++i) cc4[i] = (f32x4){0.f, 0.f, 0.f, 0.f};
    #pragma unroll
    for (int ks = 0; ks < 2; ++ks) {
      int pxb = w*64 + ks*32 + lg*8;
      bf16x8 aq[2], ak[2];
      aq[0] = *(const bf16x8*)(buf1 + (size_t)lr*264 + pxb);
      aq[1] = *(const bf16x8*)(buf1 + (size_t)(16 + lr)*264 + pxb);
      ak[0] = *(const bf16x8*)(buf1 + (size_t)(24 + lr)*264 + pxb);
      ak[1] = *(const bf16x8*)(buf1 + (size_t)(40 + lr)*264 + pxb);
      cc4[0] = MFMA16(aq[0], ak[0], cc4[0]);
      cc4[1] = MFMA16(aq[0], ak[1], cc4[1]);
      cc4[2] = MFMA16(aq[1], ak[0], cc4[2]);
      cc4[3] = MFMA16(aq[1], ak[1], cc4[3]);
      cc4[4] = MFMA16(aq[0], aq[0], cc4[4]);   // qq: diag c 0-15
      cc4[5] = MFMA16(aq[1], aq[1], cc4[5]);   // qq: diag c 16-23
      cc4[6] = MFMA16(ak[0], ak[0], cc4[6]);   // kk: diag d 0-15
      cc4[7] = MFMA16(ak[1], ak[1], cc4[7]);   // kk: diag d 16-23
    }
    // stage cross tiles [w][tile][row*17+col] + diag [w][qk][ch]
    #pragma unroll
    for (int tile2 = 0; tile2 < 4; ++tile2) {
      float* sp = stg + w*1088 + tile2*272 + lr;
      #pragma unroll
      for (int r = 0; r < 4; ++r)
        sp[(lg*4 + r)*17] = cc4[tile2][r];
    }
    {
      int r = lr - lg*4;
      if (r >= 0 && r < 4) {
        stg[4352 + w*96 + lr]      = cc4[4][r];
        stg[4352 + w*96 + 48 + lr] = cc4[6][r];
        if (lr < 8) {
          stg[4352 + w*96 + 16 + lr]      = cc4[5][r];
          stg[4352 + w*96 + 48 + 16 + lr] = cc4[7][r];
        }
      }
    }
    __syncthreads();
    float* pdst = partials + (((size_t)bb*256 + tile)*8 + g) * 640;
    for (int e = t; e < 624; e += 256) {
      float s = 0.f;
      if (e < 576) {
        int c = e / 24, d = e % 24;
        int off = ((c >> 4)*2 + (d >> 4))*272 + (c & 15)*17 + (d & 15);
        #pragma unroll
        for (int w2 = 0; w2 < 4; ++w2) s += stg[w2*1088 + off];
      } else {
        int cc2 = e - 576;                  // 0-23 q, 24-47 k
        int qk = cc2 / 24, ch = cc2 % 24;
        #pragma unroll
        for (int w2 = 0; w2 < 4; ++w2) s += stg[4352 + w2*96 + qk*48 + ch];
      }
      pdst[e] = s;
    }
  } else {
    u16* dst = vd + (size_t)bb * (65536*192);
    #pragma unroll
    for (int i = 0; i < 6; ++i) {
      int j = t + (i << 8);
      int pp = j / 6, c16 = j % 6;
      int py = pp >> 4, px = pp & 15;
      size_t s = (size_t)(y0 + py)*256 + (x0 + px);
      uint4 v = *(const uint4*)(buf1 + pp*48 + py*24 + c16*8);
      *(uint4*)(dst + s*192 + (g - 8)*48 + c16*8) = v;
    }
  }
}

// ---------------- K3a: reduce Gram partials (8 chunks of 32 blocks) -----------------
__global__ __launch_bounds__(256) void k3a(
    const float* __restrict__ partials, float* __restrict__ G2) {
  int bb = blockIdx.x, h = blockIdx.y, ch = blockIdx.z;  // 4,8,8
  int t = threadIdx.x;
  for (int e = t; e < 624; e += 256) {
    const float* p = partials + ((size_t)(bb*256 + ch*32)*8 + h)*640 + e;
    float s = 0.f;
    #pragma unroll 4
    for (int blk = 0; blk < 32; ++blk) s += p[(size_t)blk * (8*640)];
    G2[(size_t)((bb*8 + h)*8 + ch)*640 + e] = s;
  }
}

// ---------------- K3b: norms + softmax + fold proj into M (per bb,h block) ---------
__global__ __launch_bounds__(256) void k3b(
    const float* __restrict__ G2, const float* __restrict__ scale,
    const float* __restrict__ proj_w, u16* __restrict__ M) {
  int bb = blockIdx.x, h = blockIdx.y;
  int t = threadIdx.x;
  __shared__ float Gh[640];
  __shared__ float attn[24*24];
  for (int j = t; j < 640; j += 256) {
    float s = 0.f;
    #pragma unroll
    for (int ch = 0; ch < 8; ++ch)
      s += G2[(size_t)((bb*8 + h)*8 + ch)*640 + j];
    Gh[j] = s;
  }
  __syncthreads();
  if (t < 24) {
    int c = t;
    float qn = fmaxf(sqrtf(fmaxf(Gh[576 + c], 0.f)), 1e-12f);
    float sc = scale[h];
    float L[24];
    float mx = -1e30f;
    #pragma unroll
    for (int d = 0; d < 24; ++d) {
      float kn = fmaxf(sqrtf(fmaxf(Gh[600 + d], 0.f)), 1e-12f);
      L[d] = Gh[c*24 + d] / (qn * kn) * sc;
      mx = fmaxf(mx, L[d]);
    }
    float ssum = 0.f;
    #pragma unroll
    for (int d = 0; d < 24; ++d) { L[d] = __expf(L[d] - mx); ssum += L[d]; }
    float inv = 1.f / ssum;
    #pragma unroll
    for (int d = 0; d < 24; ++d) attn[c*24 + d] = L[d] * inv;
  }
  __syncthreads();
  // M[co][h*24+d] = sum_c P[co][h*24+c] * attn[c][d]   (4608 entries)
  for (int j = t; j < 4608; j += 256) {
    int co = j / 24, d = j % 24;
    const float* Pr = proj_w + co*192 + h*24;
    float s = 0.f;
    #pragma unroll
    for (int c = 0; c < 24; ++c) s += Pr[c] * attn[c*24 + d];
    M[(size_t)bb*36864 + co*192 + h*24 + d] = f2bf(s);
  }
}

// ---------------- K4: y = M_b @ v + proj_b — zero-LDS, zero-barrier GEMM -----------
__global__ __launch_bounds__(256) void k4_out(
    const u16* __restrict__ vd, const u16* __restrict__ M,
    const float* __restrict__ proj_b, float* __restrict__ out) {
  int p = blockIdx.x;                 // 4096, XCD-swizzled
  int xcd = p & 7, q = p >> 3;
  int pr = xcd*512 + q;               // 0..4095
  int bb = pr >> 10, nb = pr & 1023;
  int s0 = nb << 6;                   // 64 pixels
  int t = threadIdx.x;
  int lane = t & 63, wid = t >> 6;    // wave = 48 M-rows x 64 px
  int lg = lane >> 4, lr = lane & 15;

  const u16* Mb = M + (size_t)bb*36864;
  const u16* Bs = vd + ((size_t)bb*65536 + s0)*192;

  f32x4 acc[3][4];
  #pragma unroll
  for (int mt = 0; mt < 3; ++mt)
    #pragma unroll
    for (int nt = 0; nt < 4; ++nt)
      acc[mt][nt] = (f32x4){0.f, 0.f, 0.f, 0.f};

  #pragma unroll
  for (int ks = 0; ks < 6; ++ks) {
    bf16x8 bf[4], af[3];
    #pragma unroll
    for (int nt = 0; nt < 4; ++nt)
      bf[nt] = *(const bf16x8*)(Bs + (size_t)(nt*16 + lr)*192 + ks*32 + lg*8);
    #pragma unroll
    for (int mt = 0; mt < 3; ++mt)
      af[mt] = *(const bf16x8*)(Mb + (size_t)(wid*48 + mt*16 + lr)*192 + ks*32 + lg*8);
    #pragma unroll
    for (int mt = 0; mt < 3; ++mt)
      #pragma unroll
      for (int nt = 0; nt < 4; ++nt)
        acc[mt][nt] = MFMA16(af[mt], bf[nt], acc[mt][nt]);
  }

  float* dst = out + (size_t)bb*(192*65536) + s0;
  #pragma unroll
  for (int mt = 0; mt < 3; ++mt) {
    int m0 = wid*48 + mt*16 + lg*4;
    #pragma unroll
    for (int r = 0; r < 4; ++r) {
      float bias = proj_b[m0 + r];
      #pragma unroll
      for (int nt = 0; nt < 4; ++nt)
        dst[(size_t)(m0 + r)*65536 + nt*16 + lr] = acc[mt][nt][r] + bias;
    }
  }
}

extern "C" void kernel_launch(void* const* d_in, const int* in_sizes, int n_in,
                              void* d_out, int out_size, void* d_ws, size_t ws_size,
                              hipStream_t stream) {
  (void)in_sizes; (void)n_in; (void)out_size; (void)ws_size;
  const float* x      = (const float*)d_in[0];
  const float* qkv_w  = (const float*)d_in[1];
  const float* qkv_b  = (const float*)d_in[2];
  const float* dw_w   = (const float*)d_in[3];
  const float* dw_b   = (const float*)d_in[4];
  const float* scale  = (const float*)d_in[5];
  const float* proj_w = (const float*)d_in[6];
  const float* proj_b = (const float*)d_in[7];
  float* out = (float*)d_out;
  char* ws = (char*)d_ws;

  u16*   qkv1     = (u16*)(ws);                       // interleaved [b][g][s][48]
  u16*   vd       = (u16*)(ws + 301989888ULL);
  float* partials = (float*)(ws + 402653184ULL);
  u16*   Wb       = (u16*)(ws + 402653184ULL);
  float* Bp       = (float*)(ws + 402653184ULL + 221184ULL);
  float* G2       = (float*)(ws);
  u16*   M        = (u16*)(ws + 1048576ULL);

  k0_wb<<<dim3(432), dim3(256), 0, stream>>>(qkv_w, qkv_b, Wb, Bp);
  k1_qkv<<<dim3(2048), dim3(512), 0, stream>>>(x, Wb, Bp, qkv1);
  k2_dw<<<dim3(256, 12, 4), dim3(256), 0, stream>>>(qkv1, dw_w, dw_b, vd, partials);
  k3a<<<dim3(4, 8, 8), dim3(256), 0, stream>>>(partials, G2);
  k3b<<<dim3(4, 8), dim3(256), 0, stream>>>(G2, scale, proj_w, M);
  k4_out<<<dim3(4096), dim3(256), 0, stream>>>(vd, M, proj_b, out);
}